// Round 1
// 3184.917 us; speedup vs baseline: 2.9543x; 2.9543x over previous
//
#include <hip/hip_runtime.h>

#define SEQ   2048
#define BATCH 128
#define INDIM 128
#define HID   256
#define BH    (BATCH * HID)
#define SB    (SEQ * BATCH)

// ---------------------------------------------------------------------------
// Phase 1: xin[t,b,j] = dot(x[t,b,:], W_in[j,:]) + b_in[j] + b_h[j]
// Written IN-PLACE into out[0 .. SEQ*BH). Fully parallel GEMM: rows = (t,b)
// flattened (262144 rows), 64 rows per block, one thread per output column.
// W_in row j lives in 128 VGPRs (fits: ~160 VGPR total, no spill).
// ---------------------------------------------------------------------------
#define P1_ROWS 64

__global__ __launch_bounds__(256, 2) void xin_gemm(
    const float* __restrict__ x, const float* __restrict__ W_in,
    const float* __restrict__ b_in, const float* __restrict__ b_h,
    float* __restrict__ out) {
  __shared__ __align__(16) float xs[P1_ROWS * INDIM];  // 32 KB
  const int j  = threadIdx.x;         // output column (hidden unit)
  const int r0 = blockIdx.x * P1_ROWS;

  // W_in[j,:] -> registers
  float w[INDIM];
  {
    const float4* wg = (const float4*)(W_in + (size_t)j * INDIM);
#pragma unroll
    for (int k4 = 0; k4 < INDIM / 4; ++k4) {
      float4 v = wg[k4];
      w[4 * k4 + 0] = v.x; w[4 * k4 + 1] = v.y;
      w[4 * k4 + 2] = v.z; w[4 * k4 + 3] = v.w;
    }
  }

  // stage 64 rows of x into LDS (coalesced float4)
  {
    const float4* xg = (const float4*)(x + (size_t)r0 * INDIM);
    float4* xs4 = (float4*)xs;
#pragma unroll
    for (int q = 0; q < (P1_ROWS * INDIM / 4) / 256; ++q)  // 8 iters
      xs4[q * 256 + j] = xg[q * 256 + j];
  }
  __syncthreads();

  const float bias = b_in[j] + b_h[j];

  // 4 rows at a time: 4 independent FMA chains (ILP), broadcast LDS reads
  for (int rr = 0; rr < P1_ROWS; rr += 4) {
    float a0 = bias, a1 = bias, a2 = bias, a3 = bias;
    const float4* x0 = (const float4*)(xs + (size_t)(rr + 0) * INDIM);
    const float4* x1 = (const float4*)(xs + (size_t)(rr + 1) * INDIM);
    const float4* x2 = (const float4*)(xs + (size_t)(rr + 2) * INDIM);
    const float4* x3 = (const float4*)(xs + (size_t)(rr + 3) * INDIM);
#pragma unroll
    for (int k4 = 0; k4 < INDIM / 4; ++k4) {
      float4 v0 = x0[k4], v1 = x1[k4], v2 = x2[k4], v3 = x3[k4];
      a0 = fmaf(w[4*k4+0], v0.x, a0); a0 = fmaf(w[4*k4+1], v0.y, a0);
      a0 = fmaf(w[4*k4+2], v0.z, a0); a0 = fmaf(w[4*k4+3], v0.w, a0);
      a1 = fmaf(w[4*k4+0], v1.x, a1); a1 = fmaf(w[4*k4+1], v1.y, a1);
      a1 = fmaf(w[4*k4+2], v1.z, a1); a1 = fmaf(w[4*k4+3], v1.w, a1);
      a2 = fmaf(w[4*k4+0], v2.x, a2); a2 = fmaf(w[4*k4+1], v2.y, a2);
      a2 = fmaf(w[4*k4+2], v2.z, a2); a2 = fmaf(w[4*k4+3], v2.w, a2);
      a3 = fmaf(w[4*k4+0], v3.x, a3); a3 = fmaf(w[4*k4+1], v3.y, a3);
      a3 = fmaf(w[4*k4+2], v3.z, a3); a3 = fmaf(w[4*k4+3], v3.w, a3);
    }
    out[(size_t)(r0 + rr + 0) * HID + j] = a0;  // coalesced stores
    out[(size_t)(r0 + rr + 1) * HID + j] = a1;
    out[(size_t)(r0 + rr + 2) * HID + j] = a2;
    out[(size_t)(r0 + rr + 3) * HID + j] = a3;
  }
}

// ---------------------------------------------------------------------------
// Phase 2: recurrence. One block per batch element, 512 threads = 2 threads
// per hidden unit (lane-adjacent pair p=0/1). Thread (j,p) holds
// W_h[j, 128p .. 128p+127] in 128 VGPRs (no spill, ~170 VGPR -> 2 waves/SIMD).
// h double-buffered in LDS -> ONE barrier per step. Reads xin from out[t]
// (written by phase 1), overwrites it with h_t after use.
// ---------------------------------------------------------------------------
__global__ __launch_bounds__(512, 2) void ctrnn_rec(
    const float* __restrict__ h0, const float* __restrict__ W_h,
    float* out) {
  __shared__ __align__(16) float hs[2][HID];
  const int b   = blockIdx.x;
  const int tid = threadIdx.x;
  const int j   = tid >> 1;   // hidden unit
  const int p   = tid & 1;    // which half of the dot product

  // W_h[j, 128p : 128p+128) -> registers
  float w[HID / 2];
  {
    const float4* wg = (const float4*)(W_h + (size_t)j * HID + p * (HID / 2));
#pragma unroll
    for (int k4 = 0; k4 < HID / 8; ++k4) {  // 32 float4
      float4 v = wg[k4];
      w[4 * k4 + 0] = v.x; w[4 * k4 + 1] = v.y;
      w[4 * k4 + 2] = v.z; w[4 * k4 + 3] = v.w;
    }
  }

  float hj = h0[(size_t)b * HID + j];
  if (p == 0) hs[0][j] = hj;

  float* const io = out + (size_t)b * HID + j;  // this thread's column stream

  // prefetch xin[0] (both pair-threads load same addr; L1 broadcasts)
  float xr = io[0];
  __syncthreads();

  int cur = 0;
  for (int t = 0; t < SEQ; ++t) {
    // prefetch next timestep's xin early; latency hides under the FMAs
    float xrn = 0.f;
    if (t + 1 < SEQ) xrn = io[(size_t)(t + 1) * BH];

    // half dot-product: h[128p .. 128p+127] . w[:]
    // even/odd lanes read addresses 512B apart -> 2-way LDS aliasing (free)
    const float4* hv = (const float4*)(hs[cur] + p * (HID / 2));
    float a0 = 0.f, a1 = 0.f, a2 = 0.f, a3 = 0.f;
#pragma unroll
    for (int k4 = 0; k4 < HID / 8; ++k4) {
      float4 v = hv[k4];
      a0 = fmaf(w[4 * k4 + 0], v.x, a0);
      a1 = fmaf(w[4 * k4 + 1], v.y, a1);
      a2 = fmaf(w[4 * k4 + 2], v.z, a2);
      a3 = fmaf(w[4 * k4 + 3], v.w, a3);
    }
    float a = (a0 + a1) + (a2 + a3);
    a += __shfl_xor(a, 1);  // combine the two halves (in-register, no LDS)

    const float hn = fmaxf(a + xr, 0.f);  // xr already has b_in+b_h folded in
    hj = fmaf(0.1f, hn, 0.9f * hj);

    if (p == 0) {
      io[(size_t)t * BH] = hj;       // overwrite consumed xin with h_t
      hs[cur ^ 1][j] = hj;           // publish into the OTHER buffer
    }
    xr = xrn;
    cur ^= 1;
    __syncthreads();  // single barrier: makes hs[cur] visible, and fences
                      // this step's reads before next step's overwrite
  }

  if (p == 0) io[(size_t)SEQ * BH] = hj;  // h_final
}

extern "C" void kernel_launch(void* const* d_in, const int* in_sizes, int n_in,
                              void* d_out, int out_size, void* d_ws, size_t ws_size,
                              hipStream_t stream) {
  const float* x    = (const float*)d_in[0];
  const float* h0   = (const float*)d_in[1];
  const float* W_in = (const float*)d_in[2];
  const float* b_in = (const float*)d_in[3];
  const float* W_h  = (const float*)d_in[4];
  const float* b_h  = (const float*)d_in[5];
  float* out = (float*)d_out;

  // Phase 1: input projection for all timesteps (parallel GEMM, in-place
  // into out). Phase 2 on the same stream is implicitly ordered after it.
  xin_gemm<<<SB / P1_ROWS, 256, 0, stream>>>(x, W_in, b_in, b_h, out);
  ctrnn_rec<<<BATCH, 512, 0, stream>>>(h0, W_h, out);
}

// Round 2
// 2839.809 us; speedup vs baseline: 3.3133x; 1.1215x over previous
//
#include <hip/hip_runtime.h>

#define SEQ   2048
#define BATCH 128
#define INDIM 128
#define HID   256
#define BH    (BATCH * HID)
#define SB    (SEQ * BATCH)

// ---------------------------------------------------------------------------
// VALU-only 8-lane sum (lanes grouped on bits 0..2): quad_perm xor1,
// quad_perm xor2, then row_half_mirror (lane^7) which pairs the two quads.
// No ds_swizzle -> nothing goes through the LDS pipe.
// ---------------------------------------------------------------------------
template <int CTRL>
__device__ __forceinline__ float dpp_mov_f32(float v) {
  return __int_as_float(
      __builtin_amdgcn_update_dpp(0, __float_as_int(v), CTRL, 0xF, 0xF, false));
}
__device__ __forceinline__ float sum8(float v) {
  v += dpp_mov_f32<0xB1>(v);   // quad_perm [1,0,3,2]  (xor 1)
  v += dpp_mov_f32<0x4E>(v);   // quad_perm [2,3,0,1]  (xor 2)
  v += dpp_mov_f32<0x141>(v);  // row_half_mirror      (xor 7 -> pairs quads)
  return v;
}

// ---------------------------------------------------------------------------
// Phase 1: xin[t,b,j] = dot(x[t,b,:], W_in[j,:]) + b_in[j] + b_h[j]
// In-place into out[0 .. SEQ*BH). 128 threads/block, each thread handles TWO
// columns (j2, j2+128) so every broadcast LDS read of an x-row feeds 2 dot
// products: LDS instrs/block halve vs the 1-col version (the measured
// bottleneck). 256 weight VGPRs -> __launch_bounds__(128,1) (512-VGPR budget).
// ---------------------------------------------------------------------------
#define P1_ROWS 64

__global__ __launch_bounds__(128, 1) void xin_gemm(
    const float* __restrict__ x, const float* __restrict__ W_in,
    const float* __restrict__ b_in, const float* __restrict__ b_h,
    float* __restrict__ out) {
  __shared__ __align__(16) float xs[P1_ROWS * INDIM];  // 32 KB
  const int j2 = threadIdx.x;          // columns j2 and j2+128
  const int r0 = blockIdx.x * P1_ROWS;

  // two weight rows -> registers (2 x 128 = 256 VGPRs)
  float w0[INDIM], w1[INDIM];
  {
    const float4* wg0 = (const float4*)(W_in + (size_t)j2 * INDIM);
    const float4* wg1 = (const float4*)(W_in + (size_t)(j2 + 128) * INDIM);
#pragma unroll
    for (int k4 = 0; k4 < INDIM / 4; ++k4) {
      float4 v0 = wg0[k4], v1 = wg1[k4];
      w0[4*k4+0] = v0.x; w0[4*k4+1] = v0.y; w0[4*k4+2] = v0.z; w0[4*k4+3] = v0.w;
      w1[4*k4+0] = v1.x; w1[4*k4+1] = v1.y; w1[4*k4+2] = v1.z; w1[4*k4+3] = v1.w;
    }
  }

  // stage 64 rows of x into LDS (coalesced float4)
  {
    const float4* xg = (const float4*)(x + (size_t)r0 * INDIM);
    float4* xs4 = (float4*)xs;
#pragma unroll
    for (int q = 0; q < (P1_ROWS * INDIM / 4) / 128; ++q)  // 16 iters
      xs4[q * 128 + j2] = xg[q * 128 + j2];
  }
  __syncthreads();

  const float bias0 = b_in[j2] + b_h[j2];
  const float bias1 = b_in[j2 + 128] + b_h[j2 + 128];

  // 4 rows x 2 cols per iteration: 8 independent FMA chains, x reads reused
  for (int rr = 0; rr < P1_ROWS; rr += 4) {
    float a0 = bias0, a1 = bias0, a2 = bias0, a3 = bias0;
    float c0 = bias1, c1 = bias1, c2 = bias1, c3 = bias1;
    const float4* x0 = (const float4*)(xs + (size_t)(rr + 0) * INDIM);
    const float4* x1 = (const float4*)(xs + (size_t)(rr + 1) * INDIM);
    const float4* x2 = (const float4*)(xs + (size_t)(rr + 2) * INDIM);
    const float4* x3 = (const float4*)(xs + (size_t)(rr + 3) * INDIM);
#pragma unroll
    for (int k4 = 0; k4 < INDIM / 4; ++k4) {
      float4 v0 = x0[k4], v1 = x1[k4], v2 = x2[k4], v3 = x3[k4];
      a0 = fmaf(w0[4*k4+0], v0.x, a0); a0 = fmaf(w0[4*k4+1], v0.y, a0);
      a0 = fmaf(w0[4*k4+2], v0.z, a0); a0 = fmaf(w0[4*k4+3], v0.w, a0);
      a1 = fmaf(w0[4*k4+0], v1.x, a1); a1 = fmaf(w0[4*k4+1], v1.y, a1);
      a1 = fmaf(w0[4*k4+2], v1.z, a1); a1 = fmaf(w0[4*k4+3], v1.w, a1);
      a2 = fmaf(w0[4*k4+0], v2.x, a2); a2 = fmaf(w0[4*k4+1], v2.y, a2);
      a2 = fmaf(w0[4*k4+2], v2.z, a2); a2 = fmaf(w0[4*k4+3], v2.w, a2);
      a3 = fmaf(w0[4*k4+0], v3.x, a3); a3 = fmaf(w0[4*k4+1], v3.y, a3);
      a3 = fmaf(w0[4*k4+2], v3.z, a3); a3 = fmaf(w0[4*k4+3], v3.w, a3);
      c0 = fmaf(w1[4*k4+0], v0.x, c0); c0 = fmaf(w1[4*k4+1], v0.y, c0);
      c0 = fmaf(w1[4*k4+2], v0.z, c0); c0 = fmaf(w1[4*k4+3], v0.w, c0);
      c1 = fmaf(w1[4*k4+0], v1.x, c1); c1 = fmaf(w1[4*k4+1], v1.y, c1);
      c1 = fmaf(w1[4*k4+2], v1.z, c1); c1 = fmaf(w1[4*k4+3], v1.w, c1);
      c2 = fmaf(w1[4*k4+0], v2.x, c2); c2 = fmaf(w1[4*k4+1], v2.y, c2);
      c2 = fmaf(w1[4*k4+2], v2.z, c2); c2 = fmaf(w1[4*k4+3], v2.w, c2);
      c3 = fmaf(w1[4*k4+0], v3.x, c3); c3 = fmaf(w1[4*k4+1], v3.y, c3);
      c3 = fmaf(w1[4*k4+2], v3.z, c3); c3 = fmaf(w1[4*k4+3], v3.w, c3);
    }
    out[(size_t)(r0 + rr + 0) * HID + j2] = a0;
    out[(size_t)(r0 + rr + 1) * HID + j2] = a1;
    out[(size_t)(r0 + rr + 2) * HID + j2] = a2;
    out[(size_t)(r0 + rr + 3) * HID + j2] = a3;
    out[(size_t)(r0 + rr + 0) * HID + j2 + 128] = c0;
    out[(size_t)(r0 + rr + 1) * HID + j2 + 128] = c1;
    out[(size_t)(r0 + rr + 2) * HID + j2 + 128] = c2;
    out[(size_t)(r0 + rr + 3) * HID + j2 + 128] = c3;
  }
}

// ---------------------------------------------------------------------------
// Phase 2: recurrence. 512 threads/block: tid = 8g + q. Thread handles R=4
// rows (4g..4g+3) x S=32 K-slice (32q..32q+31): 128 weight VGPRs, only
// 8 ds_read_b128 per thread per step (4x fewer than before). h in LDS uses a
// sliced-padded layout (36 floats per 32-slice) so the 8 distinct wave
// addresses land on disjoint bank quads -> zero conflicts. 8-lane reduction
// via DPP (VALU pipe). h kept redundantly in registers of all 8 q-lanes;
// double-buffered LDS, one barrier/step; xin prefetched 2 steps deep.
// ---------------------------------------------------------------------------
#define PADS 36  // floats per padded 32-slice (4-float pad keeps banks spread)

__global__ __launch_bounds__(512, 2) void ctrnn_rec(
    const float* __restrict__ h0, const float* __restrict__ W_h,
    float* out) {
  __shared__ __align__(16) float hs[2][8 * PADS];  // 2 x 1152 B

  const int b   = blockIdx.x;
  const int tid = threadIdx.x;
  const int q   = tid & 7;   // K-slice index
  const int g   = tid >> 3;  // row group: rows 4g..4g+3

  // W_h[4g+i][32q .. 32q+31] -> 128 VGPRs
  float w[4][32];
#pragma unroll
  for (int i = 0; i < 4; ++i) {
    const float4* wg = (const float4*)(W_h + (size_t)(4 * g + i) * HID + 32 * q);
#pragma unroll
    for (int k4 = 0; k4 < 8; ++k4) {
      float4 v = wg[k4];
      w[i][4*k4+0] = v.x; w[i][4*k4+1] = v.y;
      w[i][4*k4+2] = v.z; w[i][4*k4+3] = v.w;
    }
  }

  // this group's 4 h values, replicated across the 8 q-lanes
  float4 h4 = *(const float4*)(h0 + (size_t)b * HID + 4 * g);
  float hr[4] = {h4.x, h4.y, h4.z, h4.w};

  // padded LDS slots: unit u=4g lives in slice g>>3 at position 4*(g&7)
  float* const wslot0 = &hs[0][PADS * (g >> 3) + 4 * (g & 7)];
  float* const wslot1 = &hs[1][PADS * (g >> 3) + 4 * (g & 7)];
  const float* const rbase0 = &hs[0][PADS * q];
  const float* const rbase1 = &hs[1][PADS * q];

  if (q == 0) *(float4*)wslot0 = h4;

  float* const io = out + (size_t)b * HID + 4 * g;  // group's column stream
  // 2-deep xin prefetch (all 8 q-lanes load the same 16B; coalesced per wave)
  float4 xA = *(const float4*)(io);
  float4 xB = *(const float4*)(io + (size_t)BH);

  __syncthreads();

  auto step = [&](int t, const float* rbuf, float* wslot) {
    // prefetch xin[t+2] (guarded: never touch out[] slots this block already
    // rewrote with h, and no same-address load/store race at the tail)
    float4 xC = xA;
    if (t + 2 < SEQ) xC = *(const float4*)(io + (size_t)(t + 2) * BH);

    const float4* hv = (const float4*)rbuf;
    float a[4] = {0.f, 0.f, 0.f, 0.f};
#pragma unroll
    for (int k4 = 0; k4 < 8; ++k4) {
      float4 v = hv[k4];
#pragma unroll
      for (int i = 0; i < 4; ++i) {
        a[i] = fmaf(w[i][4*k4+0], v.x, a[i]);
        a[i] = fmaf(w[i][4*k4+1], v.y, a[i]);
        a[i] = fmaf(w[i][4*k4+2], v.z, a[i]);
        a[i] = fmaf(w[i][4*k4+3], v.w, a[i]);
      }
    }
#pragma unroll
    for (int i = 0; i < 4; ++i) a[i] = sum8(a[i]);  // full sums, uniform in q

    const float xi[4] = {xA.x, xA.y, xA.z, xA.w};
#pragma unroll
    for (int i = 0; i < 4; ++i)
      hr[i] = fmaf(0.1f, fmaxf(a[i] + xi[i], 0.f), 0.9f * hr[i]);

    if (q == 0) {
      float4 hw = make_float4(hr[0], hr[1], hr[2], hr[3]);
      *(float4*)wslot = hw;                    // publish h_t (other buffer)
      *(float4*)(io + (size_t)t * BH) = hw;    // overwrite consumed xin
    }
    xA = xB; xB = xC;
    __syncthreads();  // single barrier: publishes h_t, fences buffer reuse
  };

  for (int t = 0; t < SEQ; t += 2) {  // SEQ even: buffers alternate statically
    step(t, rbase0, wslot1);
    step(t + 1, rbase1, wslot0);
  }

  if (q == 0)
    *(float4*)(io + (size_t)SEQ * BH) = make_float4(hr[0], hr[1], hr[2], hr[3]);
}

extern "C" void kernel_launch(void* const* d_in, const int* in_sizes, int n_in,
                              void* d_out, int out_size, void* d_ws, size_t ws_size,
                              hipStream_t stream) {
  const float* x    = (const float*)d_in[0];
  const float* h0   = (const float*)d_in[1];
  const float* W_in = (const float*)d_in[2];
  const float* b_in = (const float*)d_in[3];
  const float* W_h  = (const float*)d_in[4];
  const float* b_h  = (const float*)d_in[5];
  float* out = (float*)d_out;

  xin_gemm<<<SB / P1_ROWS, 128, 0, stream>>>(x, W_in, b_in, b_h, out);
  ctrnn_rec<<<BATCH, 512, 0, stream>>>(h0, W_h, out);
}

// Round 3
// 2839.030 us; speedup vs baseline: 3.3142x; 1.0003x over previous
//
#include <hip/hip_runtime.h>

#define SEQ   2048
#define BATCH 128
#define INDIM 128
#define HID   256
#define BH    (BATCH * HID)
#define SB    (SEQ * BATCH)

// ---------------------------------------------------------------------------
// VALU-only 8-lane butterfly sum over lane bits 0..2 (DPP, no LDS pipe).
// ---------------------------------------------------------------------------
template <int CTRL>
__device__ __forceinline__ float dpp_mov_f32(float v) {
  return __int_as_float(
      __builtin_amdgcn_update_dpp(0, __float_as_int(v), CTRL, 0xF, 0xF, false));
}
__device__ __forceinline__ float sum8(float v) {
  v += dpp_mov_f32<0xB1>(v);   // quad_perm xor1
  v += dpp_mov_f32<0x4E>(v);   // quad_perm xor2
  v += dpp_mov_f32<0x141>(v);  // row_half_mirror (xor7 -> pairs quads)
  return v;
}

// ---------------------------------------------------------------------------
// Phase 1: out[r,n] = dot(x[r,:], W_in[n,:]) + b_in[n] + b_h[n], r in [0,SB).
// Tiled fp32 GEMM: 128x128 tile, K staged in 2 chunks of 64, 256 threads,
// 8x8 outputs/thread (~150 VGPR -> 2 waves/SIMD; 64 KB LDS -> 2 blocks/CU).
// A/B rows stored rotated by 4*((row>>3)&7) floats within the 64-float row so
// the 16 row-group addresses of one ds_read_b128 spread 2-way (not 4-way).
// ---------------------------------------------------------------------------
#define TM 128
#define TN 128
#define KC 64

__global__ __launch_bounds__(256, 2) void xin_gemm(
    const float* __restrict__ x, const float* __restrict__ W_in,
    const float* __restrict__ b_in, const float* __restrict__ b_h,
    float* __restrict__ out) {
  __shared__ __align__(16) float As[TM * KC];  // x tile, [r][rotated c]
  __shared__ __align__(16) float Bs[TN * KC];  // W tile, [n][rotated c]

  const int tid = threadIdx.x;
  const int bm  = blockIdx.x >> 1;   // 2048 row-blocks
  const int bn  = blockIdx.x & 1;    // 2 col-blocks (consecutive -> L2 reuse of x)
  const int mg  = tid & 15;          // rows 8*mg .. 8*mg+7 of tile
  const int ng  = tid >> 4;          // cols 8*ng .. 8*ng+7 of tile
  const int rotA = 4 * (mg & 7);
  const int rotB = 4 * (ng & 7);

  const float4* xg = (const float4*)(x + (size_t)bm * TM * INDIM);
  const float4* wg = (const float4*)(W_in + (size_t)bn * TN * INDIM);

  float acc[8][8] = {};

  for (int h = 0; h < 2; ++h) {  // two K-chunks of 64
    // ---- stage A and B (2048 float4 each; coalesced reads, rotated writes)
#pragma unroll
    for (int s = 0; s < 8; ++s) {
      const int id = tid + 256 * s;   // 0..2047
      const int r  = id >> 4;         // 0..127
      const int c4 = id & 15;         // 0..15 (float4 index within K-chunk)
      const int rc = (4 * c4 + 4 * ((r >> 3) & 7)) & (KC - 1);
      float4 va = xg[(size_t)r * 32 + c4 + 16 * h];
      *(float4*)(As + r * KC + rc) = va;
      float4 vb = wg[(size_t)r * 32 + c4 + 16 * h];
      *(float4*)(Bs + r * KC + rc) = vb;
    }
    __syncthreads();

    // ---- compute: 16 k4-steps, 16 b128 reads + 256 FMA per step per wave
#pragma unroll 4
    for (int k4 = 0; k4 < KC / 4; ++k4) {
      const int ca = (4 * k4 + rotA) & (KC - 1);
      const int cb = (4 * k4 + rotB) & (KC - 1);
      float4 a[8], bb[8];
#pragma unroll
      for (int i = 0; i < 8; ++i)
        a[i] = *(const float4*)(As + (8 * mg + i) * KC + ca);
#pragma unroll
      for (int j = 0; j < 8; ++j)
        bb[j] = *(const float4*)(Bs + (8 * ng + j) * KC + cb);
#pragma unroll
      for (int i = 0; i < 8; ++i)
#pragma unroll
        for (int j = 0; j < 8; ++j) {
          acc[i][j] = fmaf(a[i].x, bb[j].x, acc[i][j]);
          acc[i][j] = fmaf(a[i].y, bb[j].y, acc[i][j]);
          acc[i][j] = fmaf(a[i].z, bb[j].z, acc[i][j]);
          acc[i][j] = fmaf(a[i].w, bb[j].w, acc[i][j]);
        }
    }
    __syncthreads();  // before restaging
  }

  // ---- epilogue: bias + store
  const int row0 = bm * TM + 8 * mg;
  const int n0   = bn * TN + 8 * ng;
  float bi[8];
#pragma unroll
  for (int j = 0; j < 8; ++j) bi[j] = b_in[n0 + j] + b_h[n0 + j];
#pragma unroll
  for (int i = 0; i < 8; ++i) {
    float4 lo = make_float4(acc[i][0] + bi[0], acc[i][1] + bi[1],
                            acc[i][2] + bi[2], acc[i][3] + bi[3]);
    float4 hi = make_float4(acc[i][4] + bi[4], acc[i][5] + bi[5],
                            acc[i][6] + bi[6], acc[i][7] + bi[7]);
    float* o = out + (size_t)(row0 + i) * HID + n0;
    *(float4*)o       = lo;
    *(float4*)(o + 4) = hi;
  }
}

// ---------------------------------------------------------------------------
// Phase 2: recurrence. 256 threads: tid = 8g + q; thread owns R=8 rows
// (8g..8g+7) x S=32 K-slice (32q..32q+31). 256 weight floats/thread (unified
// VGPR+AGPR file @ 1 wave/SIMD). LDS per step: 8 ds_read_b128/thread ->
// 32 wave-instrs/CU (half of round 2). Padded slice layout (36 floats/slice)
// keeps reads conflict-free. sum8 via DPP; double-buffered h, 1 barrier/step;
// xin prefetched 2 steps deep from out[] (in-place, overwritten with h_t).
// ---------------------------------------------------------------------------
#define PADS 36

__global__ __launch_bounds__(256, 1) void ctrnn_rec(
    const float* __restrict__ h0, const float* __restrict__ W_h,
    float* out) {
  __shared__ __align__(16) float hs[2][8 * PADS];

  const int b   = blockIdx.x;
  const int tid = threadIdx.x;
  const int q   = tid & 7;    // K-slice
  const int g   = tid >> 3;   // row group: rows 8g..8g+7

  // W_h[8g+i][32q..32q+31] -> 256 floats
  float w[8][32];
#pragma unroll
  for (int i = 0; i < 8; ++i) {
    const float4* wg = (const float4*)(W_h + (size_t)(8 * g + i) * HID + 32 * q);
#pragma unroll
    for (int k4 = 0; k4 < 8; ++k4) {
      float4 v = wg[k4];
      w[i][4*k4+0] = v.x; w[i][4*k4+1] = v.y;
      w[i][4*k4+2] = v.z; w[i][4*k4+3] = v.w;
    }
  }

  // this group's 8 h values, replicated across the 8 q-lanes
  float hr[8];
  {
    float4 h40 = *(const float4*)(h0 + (size_t)b * HID + 8 * g);
    float4 h41 = *(const float4*)(h0 + (size_t)b * HID + 8 * g + 4);
    hr[0]=h40.x; hr[1]=h40.y; hr[2]=h40.z; hr[3]=h40.w;
    hr[4]=h41.x; hr[5]=h41.y; hr[6]=h41.z; hr[7]=h41.w;
  }

  // h[u], u=8g+i lives in slice u>>5 = g>>2 at offset u&31 = 8*(g&3)+i
  float* const wslot0 = &hs[0][PADS * (g >> 2) + 8 * (g & 3)];
  float* const wslot1 = &hs[1][PADS * (g >> 2) + 8 * (g & 3)];
  const float* const rb0 = &hs[0][PADS * q];
  const float* const rb1 = &hs[1][PADS * q];

  if (q == 0) {
    *(float4*)wslot0       = make_float4(hr[0], hr[1], hr[2], hr[3]);
    *(float4*)(wslot0 + 4) = make_float4(hr[4], hr[5], hr[6], hr[7]);
  }

  float* const io = out + (size_t)b * HID + 8 * g;  // group's column stream
  // 2-deep xin prefetch (2 float4 per step)
  float4 xA0 = ((const float4*)io)[0];
  float4 xA1 = ((const float4*)io)[1];
  float4 xB0 = ((const float4*)(io + (size_t)BH))[0];
  float4 xB1 = ((const float4*)(io + (size_t)BH))[1];

  __syncthreads();

  auto step = [&](int t, const float* rbuf, float* wslot) {
    float4 xC0 = xA0, xC1 = xA1;
    if (t + 2 < SEQ) {
      xC0 = ((const float4*)(io + (size_t)(t + 2) * BH))[0];
      xC1 = ((const float4*)(io + (size_t)(t + 2) * BH))[1];
    }

    const float4* hv = (const float4*)rbuf;  // slice q, conflict-free
    float a[8] = {0.f, 0.f, 0.f, 0.f, 0.f, 0.f, 0.f, 0.f};
#pragma unroll
    for (int k4 = 0; k4 < 8; ++k4) {
      float4 v = hv[k4];
#pragma unroll
      for (int i = 0; i < 8; ++i) {
        a[i] = fmaf(w[i][4*k4+0], v.x, a[i]);
        a[i] = fmaf(w[i][4*k4+1], v.y, a[i]);
        a[i] = fmaf(w[i][4*k4+2], v.z, a[i]);
        a[i] = fmaf(w[i][4*k4+3], v.w, a[i]);
      }
    }
#pragma unroll
    for (int i = 0; i < 8; ++i) a[i] = sum8(a[i]);  // full sums in all q-lanes

    const float xi[8] = {xA0.x, xA0.y, xA0.z, xA0.w,
                         xA1.x, xA1.y, xA1.z, xA1.w};
#pragma unroll
    for (int i = 0; i < 8; ++i)
      hr[i] = fmaf(0.1f, fmaxf(a[i] + xi[i], 0.f), 0.9f * hr[i]);

    if (q == 0) {
      float4 lo = make_float4(hr[0], hr[1], hr[2], hr[3]);
      float4 hi = make_float4(hr[4], hr[5], hr[6], hr[7]);
      *(float4*)wslot       = lo;   // publish h_t into the OTHER buffer
      *(float4*)(wslot + 4) = hi;
      float* o = io + (size_t)t * BH;
      *(float4*)o       = lo;       // overwrite consumed xin with h_t
      *(float4*)(o + 4) = hi;
    }
    xA0 = xB0; xA1 = xB1; xB0 = xC0; xB1 = xC1;
    __syncthreads();  // single barrier/step: publish + fence buffer reuse
  };

  for (int t = 0; t < SEQ; t += 2) {  // SEQ even: static buffer alternation
    step(t, rb0, wslot1);
    step(t + 1, rb1, wslot0);
  }

  if (q == 0) {
    float* o = io + (size_t)SEQ * BH;
    *(float4*)o       = make_float4(hr[0], hr[1], hr[2], hr[3]);
    *(float4*)(o + 4) = make_float4(hr[4], hr[5], hr[6], hr[7]);
  }
}

extern "C" void kernel_launch(void* const* d_in, const int* in_sizes, int n_in,
                              void* d_out, int out_size, void* d_ws, size_t ws_size,
                              hipStream_t stream) {
  const float* x    = (const float*)d_in[0];
  const float* h0   = (const float*)d_in[1];
  const float* W_in = (const float*)d_in[2];
  const float* b_in = (const float*)d_in[3];
  const float* W_h  = (const float*)d_in[4];
  const float* b_h  = (const float*)d_in[5];
  float* out = (float*)d_out;

  xin_gemm<<<(SB / TM) * (HID / TN), 256, 0, stream>>>(x, W_in, b_in, b_h, out);
  ctrnn_rec<<<BATCH, 256, 0, stream>>>(h0, W_h, out);
}

// Round 5
// 2422.654 us; speedup vs baseline: 3.8838x; 1.1719x over previous
//
#include <hip/hip_runtime.h>

#define SEQ   2048
#define BATCH 128
#define INDIM 128
#define HID   256
#define BH    (BATCH * HID)
#define SB    (SEQ * BATCH)

// ---------------------------------------------------------------------------
// VALU-only 16-lane butterfly sum over lane bits 0..3 (DPP, no LDS pipe).
// After it, all 16 lanes of the group hold the full sum.
// ---------------------------------------------------------------------------
template <int CTRL>
__device__ __forceinline__ float dpp_mov_f32(float v) {
  return __int_as_float(
      __builtin_amdgcn_update_dpp(0, __float_as_int(v), CTRL, 0xF, 0xF, false));
}
__device__ __forceinline__ float sum16(float v) {
  v += dpp_mov_f32<0xB1>(v);   // quad_perm [1,0,3,2]  (xor 1)
  v += dpp_mov_f32<0x4E>(v);   // quad_perm [2,3,0,1]  (xor 2)
  v += dpp_mov_f32<0x141>(v);  // row_half_mirror      (lane^7 within 8)
  v += dpp_mov_f32<0x140>(v);  // row_mirror           (lane^15 within 16)
  return v;
}

// lgkm-only barrier: publishes LDS writes WITHOUT draining vmcnt, so global
// prefetch loads / h-stores stay in flight across steps (the __syncthreads
// vmcnt(0) drain was costing ~700 cyc/step in rounds 2-3).
__device__ __forceinline__ void block_sync_lds() {
  asm volatile("s_waitcnt lgkmcnt(0)" ::: "memory");
  __builtin_amdgcn_s_barrier();
  asm volatile("" ::: "memory");
}

// ---------------------------------------------------------------------------
// Phase 1: out[r,n] = dot(x[r,:], W_in[n,:]) + b_in[n] + b_h[n], r in [0,SB).
// (unchanged from round 3: 128x128 tile, 8x8 per thread, rotated LDS rows)
// ---------------------------------------------------------------------------
#define TM 128
#define TN 128
#define KC 64

__global__ __launch_bounds__(256, 2) void xin_gemm(
    const float* __restrict__ x, const float* __restrict__ W_in,
    const float* __restrict__ b_in, const float* __restrict__ b_h,
    float* __restrict__ out) {
  __shared__ __align__(16) float As[TM * KC];
  __shared__ __align__(16) float Bs[TN * KC];

  const int tid = threadIdx.x;
  const int bm  = blockIdx.x >> 1;
  const int bn  = blockIdx.x & 1;
  const int mg  = tid & 15;
  const int ng  = tid >> 4;
  const int rotA = 4 * (mg & 7);
  const int rotB = 4 * (ng & 7);

  const float4* xg = (const float4*)(x + (size_t)bm * TM * INDIM);
  const float4* wg = (const float4*)(W_in + (size_t)bn * TN * INDIM);

  float acc[8][8] = {};

  for (int h = 0; h < 2; ++h) {
#pragma unroll
    for (int s = 0; s < 8; ++s) {
      const int id = tid + 256 * s;
      const int r  = id >> 4;
      const int c4 = id & 15;
      const int rc = (4 * c4 + 4 * ((r >> 3) & 7)) & (KC - 1);
      float4 va = xg[(size_t)r * 32 + c4 + 16 * h];
      *(float4*)(As + r * KC + rc) = va;
      float4 vb = wg[(size_t)r * 32 + c4 + 16 * h];
      *(float4*)(Bs + r * KC + rc) = vb;
    }
    __syncthreads();

#pragma unroll 4
    for (int k4 = 0; k4 < KC / 4; ++k4) {
      const int ca = (4 * k4 + rotA) & (KC - 1);
      const int cb = (4 * k4 + rotB) & (KC - 1);
      float4 a[8], bb[8];
#pragma unroll
      for (int i = 0; i < 8; ++i)
        a[i] = *(const float4*)(As + (8 * mg + i) * KC + ca);
#pragma unroll
      for (int j = 0; j < 8; ++j)
        bb[j] = *(const float4*)(Bs + (8 * ng + j) * KC + cb);
#pragma unroll
      for (int i = 0; i < 8; ++i)
#pragma unroll
        for (int j = 0; j < 8; ++j) {
          acc[i][j] = fmaf(a[i].x, bb[j].x, acc[i][j]);
          acc[i][j] = fmaf(a[i].y, bb[j].y, acc[i][j]);
          acc[i][j] = fmaf(a[i].z, bb[j].z, acc[i][j]);
          acc[i][j] = fmaf(a[i].w, bb[j].w, acc[i][j]);
        }
    }
    __syncthreads();
  }

  const int row0 = bm * TM + 8 * mg;
  const int n0   = bn * TN + 8 * ng;
  float bi[8];
#pragma unroll
  for (int j = 0; j < 8; ++j) bi[j] = b_in[n0 + j] + b_h[n0 + j];
#pragma unroll
  for (int i = 0; i < 8; ++i) {
    float4 lo = make_float4(acc[i][0] + bi[0], acc[i][1] + bi[1],
                            acc[i][2] + bi[2], acc[i][3] + bi[3]);
    float4 hi = make_float4(acc[i][4] + bi[4], acc[i][5] + bi[5],
                            acc[i][6] + bi[6], acc[i][7] + bi[7]);
    float* o = out + (size_t)(row0 + i) * HID + n0;
    *(float4*)o       = lo;
    *(float4*)(o + 4) = hi;
  }
}

// ---------------------------------------------------------------------------
// Phase 2: recurrence. 512 threads: tid = 16g + q. Thread owns R=8 rows
// (8g..8g+7) x S=16 k-slice (16q..16q+15): 128 weight floats (2 waves/SIMD),
// only 4 ds_read_b128/thread/step (32 wave-instr/CU, half of round 2).
// sum16 via DPP. Slice-padded LDS (20 floats/slice): the 16 distinct read
// addresses tile all 32 banks exactly twice -> conflict-free. Lanes q=0/q=1
// are the writers (rows 8g..8g+3 / 8g+4..8g+7). lgkm-only barrier keeps the
// 2-deep xin prefetch + h-stores in flight across steps. In-place xin->h in
// out[] as before.
// ---------------------------------------------------------------------------
#define SPAD 20  // floats per padded 16-slice

__global__ __launch_bounds__(512, 2) void ctrnn_rec(
    const float* __restrict__ h0, const float* __restrict__ W_h,
    float* out) {
  __shared__ __align__(16) float hs[2][16 * SPAD];  // 2 x 1280 B

  const int b    = blockIdx.x;
  const int tid  = threadIdx.x;
  const int q    = tid & 15;   // k-slice index / lane bits 0..3
  const int g    = tid >> 4;   // row group: rows 8g..8g+7
  const int half = q & 1;      // writer's row-half (valid for q<2)

  // W_h[8g+i][16q..16q+15] -> 128 VGPRs
  float w[8][16];
#pragma unroll
  for (int i = 0; i < 8; ++i) {
    const float4* wgp = (const float4*)(W_h + (size_t)(8 * g + i) * HID + 16 * q);
#pragma unroll
    for (int k4 = 0; k4 < 4; ++k4) {
      float4 v = wgp[k4];
      w[i][4*k4+0] = v.x; w[i][4*k4+1] = v.y;
      w[i][4*k4+2] = v.z; w[i][4*k4+3] = v.w;
    }
  }

  // this lane's 4 rows (meaningful for q<2; harmless garbage otherwise)
  float4 h4 = *(const float4*)(h0 + (size_t)b * HID + 8 * g + 4 * half);
  float hr[4] = {h4.x, h4.y, h4.z, h4.w};

  // unit u lives in slice u>>4 at offset u&15 (padded stride SPAD)
  float* const wr0 = &hs[0][SPAD * (g >> 1) + 8 * (g & 1) + 4 * half];
  float* const wr1 = &hs[1][SPAD * (g >> 1) + 8 * (g & 1) + 4 * half];
  const float* const rd0 = &hs[0][SPAD * q];
  const float* const rd1 = &hs[1][SPAD * q];

  if (q < 2) *(float4*)wr0 = h4;

  // lane's 16B column stream in out[]
  float* const io = out + (size_t)b * HID + 8 * g + 4 * half;
  float4 xA = *(const float4*)io;                  // xin[0]
  float4 xB = *(const float4*)(io + (size_t)BH);   // xin[1]

  block_sync_lds();

  auto step = [&](int t, const float* rd, float* wr) {
    // issue t+2 prefetch first; stays in flight across the barrier now
    float4 xC = xA;
    if (t + 2 < SEQ) xC = *(const float4*)(io + (size_t)(t + 2) * BH);

    const float4* hv = (const float4*)rd;  // slice q: conflict-free pattern
    float a[8] = {0.f, 0.f, 0.f, 0.f, 0.f, 0.f, 0.f, 0.f};
#pragma unroll
    for (int k4 = 0; k4 < 4; ++k4) {
      float4 v = hv[k4];
#pragma unroll
      for (int i = 0; i < 8; ++i) {
        a[i] = fmaf(w[i][4*k4+0], v.x, a[i]);
        a[i] = fmaf(w[i][4*k4+1], v.y, a[i]);
        a[i] = fmaf(w[i][4*k4+2], v.z, a[i]);
        a[i] = fmaf(w[i][4*k4+3], v.w, a[i]);
      }
    }
#pragma unroll
    for (int i = 0; i < 8; ++i) a[i] = sum16(a[i]);  // full sums, all lanes

    // lane's 4 rows: q==0 -> a[0..3], q==1 -> a[4..7] (compile-time indices)
    const float s0 = half ? a[4] : a[0];
    const float s1 = half ? a[5] : a[1];
    const float s2 = half ? a[6] : a[2];
    const float s3 = half ? a[7] : a[3];

    hr[0] = fmaf(0.1f, fmaxf(s0 + xA.x, 0.f), 0.9f * hr[0]);
    hr[1] = fmaf(0.1f, fmaxf(s1 + xA.y, 0.f), 0.9f * hr[1]);
    hr[2] = fmaf(0.1f, fmaxf(s2 + xA.z, 0.f), 0.9f * hr[2]);
    hr[3] = fmaf(0.1f, fmaxf(s3 + xA.w, 0.f), 0.9f * hr[3]);

    if (q < 2) {
      float4 hw = make_float4(hr[0], hr[1], hr[2], hr[3]);
      *(float4*)wr = hw;                        // publish into OTHER buffer
      *(float4*)(io + (size_t)t * BH) = hw;     // overwrite consumed xin
    }
    xA = xB; xB = xC;
    block_sync_lds();  // lgkm-only: publish h_t, fence buffer reuse
  };

  for (int t = 0; t < SEQ; t += 2) {  // SEQ even: static buffer alternation
    step(t, rd0, wr1);
    step(t + 1, rd1, wr0);
  }

  if (q < 2)
    *(float4*)(io + (size_t)SEQ * BH) = make_float4(hr[0], hr[1], hr[2], hr[3]);
}

extern "C" void kernel_launch(void* const* d_in, const int* in_sizes, int n_in,
                              void* d_out, int out_size, void* d_ws, size_t ws_size,
                              hipStream_t stream) {
  const float* x    = (const float*)d_in[0];
  const float* h0   = (const float*)d_in[1];
  const float* W_in = (const float*)d_in[2];
  const float* b_in = (const float*)d_in[3];
  const float* W_h  = (const float*)d_in[4];
  const float* b_h  = (const float*)d_in[5];
  float* out = (float*)d_out;

  xin_gemm<<<(SB / TM) * (HID / TN), 256, 0, stream>>>(x, W_in, b_in, b_h, out);
  ctrnn_rec<<<BATCH, 512, 0, stream>>>(h0, W_h, out);
}